// Round 1
// baseline (1505.810 us; speedup 1.0000x reference)
//
#include <hip/hip_runtime.h>

// Resonance tiling: y1 = x1 + Ham(x2, phi[:8]); y2 = x2 + Ham(y1, psi[8:])
// Per-(row,tile) local. x: [65536, 256, 4] f32. Weights [16,16,16,4] f32.
//
// Thread map: block=256 threads, tid = r2*128 + t*16 + j  (r2: row-in-pair,
// t: tile 0..7, j: output quat col 0..15). Each thread keeps both weight
// columns phi[t][:,j], psi[8+t][:,j] in registers (32 float4).
// Rows staged 2/iter into LDS with coalesced float4 loads, double-buffered,
// one barrier per iter. y1 broadcast buffer is wave-local (no barrier).

__device__ __forceinline__ void ham_acc(float4& r, const float4 x, const float4 w) {
    // r += HamiltonProduct(x, w)   (x = tile operand, w = weight operand)
    r.x = fmaf(x.x,  w.x, r.x); r.x = fmaf(x.y, -w.y, r.x);
    r.x = fmaf(x.z, -w.z, r.x); r.x = fmaf(x.w, -w.w, r.x);
    r.y = fmaf(x.x,  w.y, r.y); r.y = fmaf(x.y,  w.x, r.y);
    r.y = fmaf(x.z,  w.w, r.y); r.y = fmaf(x.w, -w.z, r.y);
    r.z = fmaf(x.x,  w.z, r.z); r.z = fmaf(x.y, -w.w, r.z);
    r.z = fmaf(x.z,  w.x, r.z); r.z = fmaf(x.w,  w.y, r.z);
    r.w = fmaf(x.x,  w.w, r.w); r.w = fmaf(x.y,  w.z, r.w);
    r.w = fmaf(x.z, -w.y, r.w); r.w = fmaf(x.w,  w.x, r.w);
}

__global__ __launch_bounds__(256, 2)
void resonance_kernel(const float4* __restrict__ x,
                      const float4* __restrict__ phi,
                      const float4* __restrict__ psi,
                      float4* __restrict__ out,
                      int npairs) {
    __shared__ float4 xs[2][2][256];   // [buf][row-in-pair][quat]
    __shared__ float4 y1s[2][128];     // [row-in-pair][t*16+j] — wave-local use

    const int tid = threadIdx.x;
    const int r2  = tid >> 7;          // 0..1
    const int tj  = tid & 127;         // t*16 + j
    const int t   = tj >> 4;           // 0..7
    const int j   = tj & 15;           // 0..15

    // Weight columns into registers (constant-indexed -> VGPRs).
    float4 pc[16], qc[16];
#pragma unroll
    for (int i = 0; i < 16; ++i) {
        pc[i] = phi[(t * 16 + i) * 16 + j];          // phi[t][i][j]
        qc[i] = psi[((8 + t) * 16 + i) * 16 + j];    // psi[8+t][i][j]
    }

    int p = blockIdx.x;
    float4 v0, v1;
    if (p < npairs) {
        v0 = x[(size_t)(p * 2 + 0) * 256 + tid];
        v1 = x[(size_t)(p * 2 + 1) * 256 + tid];
    }

    int buf = 0;
    while (p < npairs) {
        xs[buf][0][tid] = v0;
        xs[buf][1][tid] = v1;
        __syncthreads();

        const int pn = p + gridDim.x;
        if (pn < npairs) {           // prefetch next row pair (in flight)
            v0 = x[(size_t)(pn * 2 + 0) * 256 + tid];
            v1 = x[(size_t)(pn * 2 + 1) * 256 + tid];
        }

        const float4* xr = xs[buf][r2];
        const size_t row = (size_t)(p * 2 + r2);

        // ---- stage 1: y1[j] = x1[j] + sum_i Ham(x2[i], phi[t][i][j]) ----
        float4 acc = xr[tj];                       // x1 quat j
#pragma unroll
        for (int i = 0; i < 16; ++i) {
            float4 q = xr[128 + t * 16 + i];       // x2 quat i (16-lane bcast)
            ham_acc(acc, q, pc[i]);
        }
        y1s[r2][tj] = acc;                         // wave-local exchange
        out[row * 256 + tj] = acc;                 // y1 half of output

        // ---- stage 2: y2[j] = x2[j] + sum_i Ham(y1[i], psi[8+t][i][j]) ----
        float4 acc2 = xr[128 + tj];                // x2 quat j
        __builtin_amdgcn_wave_barrier();           // keep LDS write<->read order
#pragma unroll
        for (int i = 0; i < 16; ++i) {
            float4 q = y1s[r2][t * 16 + i];        // y1 quat i (16-lane bcast)
            ham_acc(acc2, q, qc[i]);
        }
        out[row * 256 + 128 + tj] = acc2;          // y2 half of output

        buf ^= 1;
        p = pn;
    }
}

extern "C" void kernel_launch(void* const* d_in, const int* in_sizes, int n_in,
                              void* d_out, int out_size, void* d_ws, size_t ws_size,
                              hipStream_t stream) {
    const float4* x   = (const float4*)d_in[0];
    const float4* phi = (const float4*)d_in[1];
    const float4* psi = (const float4*)d_in[2];
    float4* out = (float4*)d_out;

    const int rows   = in_sizes[0] / (256 * 4);   // 65536
    const int npairs = rows / 2;                  // 32768
    const int blocks = 2048;                      // 8 blocks/CU-slot, grid-stride

    resonance_kernel<<<blocks, 256, 0, stream>>>(x, phi, psi, out, npairs);
}

// Round 2
// 275.274 us; speedup vs baseline: 5.4702x; 5.4702x over previous
//
#include <hip/hip_runtime.h>

// Resonance tiling: y1 = x1 + Ham(x2, phi[:8]); y2 = x2 + Ham(y1, psi[8:])
// x: [65536, 256, 4] f32. Weights [16,16,16,4] f32. Per-(row,tile) local.
//
// Thread map: block=256, tid = r2*128 + t*16 + j. Each thread holds weight
// columns phi[t][:,j], psi[8+t][:,j] as 32 NAMED float4 registers (X-macro,
// not arrays — round 1 showed arrays go to scratch: FETCH 2.8GB of spill).
// Rows staged 2/iter into LDS, double-buffered, one barrier/iter. x2 and y1
// broadcast regions padded to 17-float4 tile stride (4 tile groups/wave ->
// disjoint bank sets, kills the 4-way conflict seen in round 1).

__device__ __forceinline__ void ham_acc(float4& r, const float4 x, const float4 w) {
    r.x = fmaf(x.x,  w.x, r.x); r.x = fmaf(x.y, -w.y, r.x);
    r.x = fmaf(x.z, -w.z, r.x); r.x = fmaf(x.w, -w.w, r.x);
    r.y = fmaf(x.x,  w.y, r.y); r.y = fmaf(x.y,  w.x, r.y);
    r.y = fmaf(x.z,  w.w, r.y); r.y = fmaf(x.w, -w.z, r.y);
    r.z = fmaf(x.x,  w.z, r.z); r.z = fmaf(x.y, -w.w, r.z);
    r.z = fmaf(x.z,  w.x, r.z); r.z = fmaf(x.w,  w.y, r.z);
    r.w = fmaf(x.x,  w.w, r.w); r.w = fmaf(x.y,  w.z, r.w);
    r.w = fmaf(x.z, -w.y, r.w); r.w = fmaf(x.w,  w.x, r.w);
}

#define W_LIST(F) F(0) F(1) F(2) F(3) F(4) F(5) F(6) F(7) \
                  F(8) F(9) F(10) F(11) F(12) F(13) F(14) F(15)

__global__ __launch_bounds__(256, 1)
void resonance_kernel(const float4* __restrict__ x,
                      const float4* __restrict__ phi,
                      const float4* __restrict__ psi,
                      float4* __restrict__ out,
                      int npairs) {
    // x1 region: slots 0..127 (unpadded). x2 region: slot 128 + t*17 + i.
    __shared__ float4 xs[2][2][264];   // [buf][row-in-pair][slot]
    __shared__ float4 y1s[2][136];     // [row-in-pair][t*17 + j]

    const int tid = threadIdx.x;
    const int r2  = tid >> 7;          // 0..1
    const int tj  = tid & 127;         // t*16 + j
    const int t   = tj >> 4;           // 0..7
    const int j   = tj & 15;           // 0..15

    // Staging slot for this thread's quat index (= tid) within a row.
    const int slot = (tid < 128) ? tid : 128 + ((tid - 128) >> 4) * 17 + ((tid - 128) & 15);

    // Weight columns as named registers — guaranteed SROA, no scratch.
#define DECLW(i) \
    float4 p##i = phi[(t * 16 + (i)) * 16 + j]; \
    float4 q##i = psi[((8 + t) * 16 + (i)) * 16 + j];
    W_LIST(DECLW)
#undef DECLW

    int p = blockIdx.x;
    float4 v0, v1;
    if (p < npairs) {
        v0 = x[(size_t)(p * 2 + 0) * 256 + tid];
        v1 = x[(size_t)(p * 2 + 1) * 256 + tid];
    }

    int buf = 0;
    while (p < npairs) {
        xs[buf][0][slot] = v0;
        xs[buf][1][slot] = v1;
        __syncthreads();

        const int pn = p + gridDim.x;
        if (pn < npairs) {               // prefetch next row pair
            v0 = x[(size_t)(pn * 2 + 0) * 256 + tid];
            v1 = x[(size_t)(pn * 2 + 1) * 256 + tid];
        }

        const float4* xr  = xs[buf][r2];
        const float4* x2p = &xr[128 + t * 17];   // padded x2 tile base
        const size_t row  = (size_t)(p * 2 + r2);

        // ---- stage 1: y1[j] = x1[j] + sum_i Ham(x2[i], phi[t][i][j]) ----
        float4 acc = xr[tj];
#define S1(i) ham_acc(acc, x2p[(i)], p##i);
        W_LIST(S1)
#undef S1
        y1s[r2][t * 17 + j] = acc;               // wave-local exchange
        out[row * 256 + tj] = acc;

        // ---- stage 2: y2[j] = x2[j] + sum_i Ham(y1[i], psi[8+t][i][j]) ----
        float4 acc2 = x2p[j];
        __builtin_amdgcn_wave_barrier();         // keep LDS write<->read order
        const float4* y1p = &y1s[r2][t * 17];
#define S2(i) ham_acc(acc2, y1p[(i)], q##i);
        W_LIST(S2)
#undef S2
        out[row * 256 + 128 + tj] = acc2;

        buf ^= 1;
        p = pn;
    }
}

extern "C" void kernel_launch(void* const* d_in, const int* in_sizes, int n_in,
                              void* d_out, int out_size, void* d_ws, size_t ws_size,
                              hipStream_t stream) {
    const float4* x   = (const float4*)d_in[0];
    const float4* phi = (const float4*)d_in[1];
    const float4* psi = (const float4*)d_in[2];
    float4* out = (float4*)d_out;

    const int rows   = in_sizes[0] / (256 * 4);   // 65536
    const int npairs = rows / 2;                  // 32768
    const int blocks = 2048;

    resonance_kernel<<<blocks, 256, 0, stream>>>(x, phi, psi, out, npairs);
}

// Round 3
// 162.691 us; speedup vs baseline: 9.2557x; 1.6920x over previous
//
#include <hip/hip_runtime.h>

// Resonance tiling: y1 = x1 + Ham(x2, phi[:8]); y2 = x2 + Ham(y1, psi[8:])
// x: [65536, 256, 4] f32. Weights [16,16,16,4] f32. Per-(row,tile) local.
//
// Round-2 lesson: 128 VGPRs of register weights capped occupancy at 2
// waves/SIMD (11.5%) and LDS latency went unhidden (VALUBusy 37%).
// New map: block = one TILE (t = blockIdx&7) x 16 rows x 16 cols.
//  - weights for this tile = 8 KB, staged once in LDS, read as free
//    2-way-broadcast ds_reads -> ~0 weight VGPRs.
//  - each 16-lane group owns one row -> x2/y1 broadcast exchange is
//    wave-internal: NO __syncthreads in the loop, waves drift freely.
//  - x2s/y1s padded to stride 17 float4: 4 rows/wave hit 4 disjoint
//    4-bank groups -> conflict-free broadcasts.

__device__ __forceinline__ void ham_acc(float4& r, const float4 x, const float4 w) {
    r.x = fmaf(x.x,  w.x, r.x); r.x = fmaf(x.y, -w.y, r.x);
    r.x = fmaf(x.z, -w.z, r.x); r.x = fmaf(x.w, -w.w, r.x);
    r.y = fmaf(x.x,  w.y, r.y); r.y = fmaf(x.y,  w.x, r.y);
    r.y = fmaf(x.z,  w.w, r.y); r.y = fmaf(x.w, -w.z, r.y);
    r.z = fmaf(x.x,  w.z, r.z); r.z = fmaf(x.y, -w.w, r.z);
    r.z = fmaf(x.z,  w.x, r.z); r.z = fmaf(x.w,  w.y, r.z);
    r.w = fmaf(x.x,  w.w, r.w); r.w = fmaf(x.y,  w.z, r.w);
    r.w = fmaf(x.z, -w.y, r.w); r.w = fmaf(x.w,  w.x, r.w);
}

#define W_LIST(F) F(0) F(1) F(2) F(3) F(4) F(5) F(6) F(7) \
                  F(8) F(9) F(10) F(11) F(12) F(13) F(14) F(15)

__global__ __launch_bounds__(256, 4)
void resonance_kernel(const float4* __restrict__ x,
                      const float4* __restrict__ phi,
                      const float4* __restrict__ psi,
                      float4* __restrict__ out,
                      int ngroups) {
    __shared__ float4 wphi[256];      // [i*16+j] = phi[t][i][j]
    __shared__ float4 wpsi[256];      // [i*16+j] = psi[8+t][i][j]
    __shared__ float4 x2s[16][17];    // [row_local][i], pad 17 -> conflict-free
    __shared__ float4 y1s[16][17];

    const int tid = threadIdx.x;
    const int t   = blockIdx.x & 7;
    const int rl  = tid >> 4;         // row-in-group 0..15 (4 per wave)
    const int j   = tid & 15;         // output quat col

    wphi[tid] = phi[t * 256 + tid];
    wpsi[tid] = psi[(8 + t) * 256 + tid];
    __syncthreads();                  // weights ready (only block-wide sync)

    const int gstride = gridDim.x >> 3;
    int g = blockIdx.x >> 3;

    float4 v1, v2;
    if (g < ngroups) {
        const size_t row = (size_t)g * 16 + rl;
        v1 = x[row * 256 + t * 16 + j];          // x1 quat j of tile t
        v2 = x[row * 256 + 128 + t * 16 + j];    // x2 quat j of tile t
    }

    while (g < ngroups) {
        x2s[rl][j] = v2;                         // wave-local exchange
        __builtin_amdgcn_wave_barrier();

        const int gn = g + gstride;
        float4 nv1, nv2;
        if (gn < ngroups) {                      // prefetch next group
            const size_t nrow = (size_t)gn * 16 + rl;
            nv1 = x[nrow * 256 + t * 16 + j];
            nv2 = x[nrow * 256 + 128 + t * 16 + j];
        }

        const size_t row = (size_t)g * 16 + rl;

        // stage 1: y1[j] = x1[j] + sum_i Ham(x2[i], phi[t][i][j])
        float4 acc = v1;
#define S1(i) ham_acc(acc, x2s[rl][(i)], wphi[(i) * 16 + j]);
        W_LIST(S1)
#undef S1
        y1s[rl][j] = acc;
        out[row * 256 + t * 16 + j] = acc;
        __builtin_amdgcn_wave_barrier();

        // stage 2: y2[j] = x2[j] + sum_i Ham(y1[i], psi[8+t][i][j])
        float4 acc2 = v2;
#define S2(i) ham_acc(acc2, y1s[rl][(i)], wpsi[(i) * 16 + j]);
        W_LIST(S2)
#undef S2
        out[row * 256 + 128 + t * 16 + j] = acc2;

        v1 = nv1; v2 = nv2;
        g = gn;
    }
}

extern "C" void kernel_launch(void* const* d_in, const int* in_sizes, int n_in,
                              void* d_out, int out_size, void* d_ws, size_t ws_size,
                              hipStream_t stream) {
    const float4* x   = (const float4*)d_in[0];
    const float4* phi = (const float4*)d_in[1];
    const float4* psi = (const float4*)d_in[2];
    float4* out = (float4*)d_out;

    const int rows    = in_sizes[0] / (256 * 4);   // 65536
    const int ngroups = rows / 16;                 // 4096 groups of 16 rows
    const int blocks  = 8 * 512;                   // tile = bid&7, chunk = bid>>3

    resonance_kernel<<<blocks, 256, 0, stream>>>(x, phi, psi, out, ngroups);
}